// Round 1
// baseline (363.626 us; speedup 1.0000x reference)
//
#include <hip/hip_runtime.h>
#include <hip/hip_bf16.h>

typedef __attribute__((ext_vector_type(8))) short sh8;
typedef __attribute__((ext_vector_type(4))) float f32x4;

#define MFMA16(a, b, c) __builtin_amdgcn_mfma_f32_16x16x32_bf16((a), (b), (c), 0, 0, 0)

__device__ __forceinline__ unsigned short f2bf(float f) {
    unsigned int u = __float_as_uint(f);
    u += 0x7fffu + ((u >> 16) & 1u);
    return (unsigned short)(u >> 16);
}

// ---------------------------------------------------------------------------
// QKV projection: qkv[M=gridY*128 x 3072] (bf16) = x[Mx1024](f32) @ W*(f32)^T
// Q part (cols < 1024) pre-scaled by 0.125 = 1/sqrt(dk).
// ---------------------------------------------------------------------------
__global__ __launch_bounds__(256) void gemm_qkv_k(
    const float* __restrict__ x, const float* __restrict__ Wq,
    const float* __restrict__ Wk, const float* __restrict__ Wv,
    unsigned short* __restrict__ qkv)
{
    __shared__ unsigned short As[128][48];
    __shared__ unsigned short Bs[128][48];
    const int tid = threadIdx.x;
    const int l = tid & 63, w = tid >> 6;
    const int wr = w >> 1, wc = w & 1;
    const long row0 = (long)blockIdx.y * 128;
    const int col0 = blockIdx.x * 128;
    const float* Wsel; int wrow0;
    if (col0 < 1024)      { Wsel = Wq; wrow0 = col0; }
    else if (col0 < 2048) { Wsel = Wk; wrow0 = col0 - 1024; }
    else                  { Wsel = Wv; wrow0 = col0 - 2048; }

    f32x4 acc[4][4] = {};
    const int fr = l & 15, fc = (l >> 4) * 8;

    for (int k0 = 0; k0 < 1024; k0 += 32) {
        __syncthreads();
#pragma unroll
        for (int p = 0; p < 4; ++p) {
            int idx = p * 256 + tid;
            int r = idx >> 3, c4 = (idx & 7) * 4;
            float4 va = *(const float4*)&x[(row0 + r) * 1024 + k0 + c4];
            ushort4 ha = { f2bf(va.x), f2bf(va.y), f2bf(va.z), f2bf(va.w) };
            *(ushort4*)&As[r][c4] = ha;
            float4 vb = *(const float4*)&Wsel[(long)(wrow0 + r) * 1024 + k0 + c4];
            ushort4 hb = { f2bf(vb.x), f2bf(vb.y), f2bf(vb.z), f2bf(vb.w) };
            *(ushort4*)&Bs[r][c4] = hb;
        }
        __syncthreads();
        sh8 af[4], bf[4];
#pragma unroll
        for (int i = 0; i < 4; ++i) {
            af[i] = *(const sh8*)&As[wr * 64 + i * 16 + fr][fc];
            bf[i] = *(const sh8*)&Bs[wc * 64 + i * 16 + fr][fc];
        }
#pragma unroll
        for (int i = 0; i < 4; ++i)
#pragma unroll
            for (int j = 0; j < 4; ++j)
                acc[i][j] = MFMA16(af[i], bf[j], acc[i][j]);
    }

    const float scale = (col0 < 1024) ? 0.125f : 1.0f;
    const int rg = (l >> 4) * 4, cg = l & 15;
#pragma unroll
    for (int i = 0; i < 4; ++i)
#pragma unroll
        for (int j = 0; j < 4; ++j) {
            long gr = row0 + wr * 64 + i * 16 + rg;
            int gc = col0 + wc * 64 + j * 16 + cg;
#pragma unroll
            for (int r = 0; r < 4; ++r)
                qkv[(gr + r) * 3072 + gc] = f2bf(acc[i][j][r] * scale);
        }
}

// ---------------------------------------------------------------------------
// Flash attention. Block: 64 q-rows for one (batch, head). 4 waves x 16 rows.
// qkv layout: row = b*2048 + s (chunk-local), cols: Q=h*64+d, K=1024+..., V=2048+...
// Q comes pre-scaled by 1/sqrt(dk). Mask additive (-1e9 where mask==0).
// ---------------------------------------------------------------------------
__global__ __launch_bounds__(256) void attn_k(
    const unsigned short* __restrict__ qkv, const int* __restrict__ mask,
    unsigned short* __restrict__ ao, int b0)
{
    __shared__ unsigned short Kl[64][72];
    __shared__ unsigned short Vt[64][72];   // transposed V, kv-chunk XOR-swizzled by d>>3
    __shared__ float bias[64];
    __shared__ unsigned short Pl[4][16][72];

    const int tid = threadIdx.x;
    const int l = tid & 63, w = tid >> 6;
    const int fr = l & 15, fcg = l >> 4;
    const int b = blockIdx.z, h = blockIdx.y, q0 = blockIdx.x * 64;
    const long base = (long)b * 2048;
    const int gmb = (b0 + b) * 2048;

    sh8 qf0, qf1;
    {
        const unsigned short* qp = &qkv[(base + q0 + w * 16 + fr) * 3072 + h * 64 + fcg * 8];
        qf0 = *(const sh8*)qp;
        qf1 = *(const sh8*)(qp + 32);
    }

    f32x4 acc[4] = {};
    float mrow[4] = { -1e30f, -1e30f, -1e30f, -1e30f };
    float lrow[4] = { 0.f, 0.f, 0.f, 0.f };

    for (int kv0 = 0; kv0 < 2048; kv0 += 64) {
        __syncthreads();
        // stage K tile (row-major, padded)
#pragma unroll
        for (int p = 0; p < 2; ++p) {
            int idx = p * 256 + tid;
            int r = idx >> 3, c8 = (idx & 7) * 8;
            uint4 v = *(const uint4*)&qkv[(base + kv0 + r) * 3072 + 1024 + h * 64 + c8];
            *(uint2*)&Kl[r][c8] = make_uint2(v.x, v.y);
            *(uint2*)&Kl[r][c8 + 4] = make_uint2(v.z, v.w);
        }
        // stage V transposed: thread handles kv rows {2*kv2, 2*kv2+1}, d = d0..d0+7
        {
            int d0 = (tid & 7) * 8, kv2 = tid >> 3;
            const unsigned short* vp = &qkv[(base + kv0 + kv2 * 2) * 3072 + 2048 + h * 64 + d0];
            uint4 v0 = *(const uint4*)vp;
            uint4 v1 = *(const uint4*)(vp + 3072);
            int sc_ = ((kv2 >> 2) ^ (tid & 7)) * 8 + (kv2 & 3) * 2;  // swizzled stored col
            unsigned int w0[4] = { v0.x, v0.y, v0.z, v0.w };
            unsigned int w1[4] = { v1.x, v1.y, v1.z, v1.w };
#pragma unroll
            for (int jj = 0; jj < 4; ++jj) {
                unsigned int pe = (w0[jj] & 0xffffu) | (w1[jj] << 16);
                unsigned int po = (w0[jj] >> 16) | (w1[jj] & 0xffff0000u);
                *(unsigned int*)&Vt[d0 + 2 * jj][sc_] = pe;
                *(unsigned int*)&Vt[d0 + 2 * jj + 1][sc_] = po;
            }
        }
        if (tid < 64) bias[tid] = (mask[gmb + kv0 + tid] == 0) ? -1e9f : 0.0f;
        __syncthreads();

        // S = Q K^T  (16 q x 64 kv per wave)
        f32x4 s[4] = {};
#pragma unroll
        for (int nf = 0; nf < 4; ++nf) {
            const unsigned short* kp = &Kl[nf * 16 + fr][fcg * 8];
            sh8 k0f = *(const sh8*)kp;
            sh8 k1f = *(const sh8*)(kp + 32);
            s[nf] = MFMA16(qf0, k0f, s[nf]);
            s[nf] = MFMA16(qf1, k1f, s[nf]);
            float badd = bias[nf * 16 + fr];
#pragma unroll
            for (int r = 0; r < 4; ++r) s[nf][r] += badd;
        }

        // online softmax per accumulator row (row = fcg*4 + reg)
#pragma unroll
        for (int reg = 0; reg < 4; ++reg) {
            float t = fmaxf(fmaxf(s[0][reg], s[1][reg]), fmaxf(s[2][reg], s[3][reg]));
#pragma unroll
            for (int off = 1; off < 16; off <<= 1) t = fmaxf(t, __shfl_xor(t, off, 64));
            float mn = fmaxf(mrow[reg], t);
            float scl = __expf(mrow[reg] - mn);
            mrow[reg] = mn;
            float ps = 0.f;
#pragma unroll
            for (int nf = 0; nf < 4; ++nf) {
                float p = __expf(s[nf][reg] - mn);
                s[nf][reg] = p;
                ps += p;
            }
#pragma unroll
            for (int off = 1; off < 16; off <<= 1) ps += __shfl_xor(ps, off, 64);
            lrow[reg] = lrow[reg] * scl + ps;
#pragma unroll
            for (int df = 0; df < 4; ++df) acc[df][reg] *= scl;
        }

        // P -> LDS (bf16) so it can be re-read in A-fragment layout
#pragma unroll
        for (int nf = 0; nf < 4; ++nf)
#pragma unroll
            for (int reg = 0; reg < 4; ++reg)
                Pl[w][fcg * 4 + reg][nf * 16 + fr] = f2bf(s[nf][reg]);

        sh8 pa0 = *(const sh8*)&Pl[w][fr][fcg * 8];
        sh8 pa1 = *(const sh8*)&Pl[w][fr][32 + fcg * 8];
#pragma unroll
        for (int df = 0; df < 4; ++df) {
            int d = df * 16 + fr;
            sh8 vf0 = *(const sh8*)&Vt[d][(fcg ^ (d >> 3)) * 8];
            sh8 vf1 = *(const sh8*)&Vt[d][((4 + fcg) ^ (d >> 3)) * 8];
            acc[df] = MFMA16(pa0, vf0, acc[df]);
            acc[df] = MFMA16(pa1, vf1, acc[df]);
        }
    }

    // epilogue: divide by softmax denom, write bf16 attn_out
#pragma unroll
    for (int df = 0; df < 4; ++df)
#pragma unroll
        for (int reg = 0; reg < 4; ++reg) {
            long gr = base + q0 + w * 16 + fcg * 4 + reg;
            int gc = h * 64 + df * 16 + fr;
            ao[gr * 1024 + gc] = f2bf(acc[df][reg] / lrow[reg]);
        }
}

// ---------------------------------------------------------------------------
// Output projection: out[Mx1024](f32) = ao[Mx1024](bf16) @ Wo(f32)^T + bo
// ---------------------------------------------------------------------------
__global__ __launch_bounds__(256) void gemm_out_k(
    const unsigned short* __restrict__ ao, const float* __restrict__ Wo,
    const float* __restrict__ bo, float* __restrict__ out)
{
    __shared__ unsigned short As[128][48];
    __shared__ unsigned short Bs[128][48];
    const int tid = threadIdx.x;
    const int l = tid & 63, w = tid >> 6;
    const int wr = w >> 1, wc = w & 1;
    const long row0 = (long)blockIdx.y * 128;
    const int col0 = blockIdx.x * 128;

    f32x4 acc[4][4] = {};
    const int fr = l & 15, fc = (l >> 4) * 8;

    for (int k0 = 0; k0 < 1024; k0 += 32) {
        __syncthreads();
#pragma unroll
        for (int p = 0; p < 2; ++p) {
            int idx = p * 256 + tid;
            int r = idx >> 2, c8 = (idx & 3) * 8;
            uint4 v = *(const uint4*)&ao[(row0 + r) * 1024 + k0 + c8];
            *(uint2*)&As[r][c8] = make_uint2(v.x, v.y);
            *(uint2*)&As[r][c8 + 4] = make_uint2(v.z, v.w);
        }
#pragma unroll
        for (int p = 0; p < 4; ++p) {
            int idx = p * 256 + tid;
            int r = idx >> 3, c4 = (idx & 7) * 4;
            float4 vb = *(const float4*)&Wo[(long)(col0 + r) * 1024 + k0 + c4];
            ushort4 hb = { f2bf(vb.x), f2bf(vb.y), f2bf(vb.z), f2bf(vb.w) };
            *(ushort4*)&Bs[r][c4] = hb;
        }
        __syncthreads();
        sh8 af[4], bf[4];
#pragma unroll
        for (int i = 0; i < 4; ++i) {
            af[i] = *(const sh8*)&As[wr * 64 + i * 16 + fr][fc];
            bf[i] = *(const sh8*)&Bs[wc * 64 + i * 16 + fr][fc];
        }
#pragma unroll
        for (int i = 0; i < 4; ++i)
#pragma unroll
            for (int j = 0; j < 4; ++j)
                acc[i][j] = MFMA16(af[i], bf[j], acc[i][j]);
    }

    const int rg = (l >> 4) * 4, cg = l & 15;
#pragma unroll
    for (int i = 0; i < 4; ++i)
#pragma unroll
        for (int j = 0; j < 4; ++j) {
            long gr = row0 + wr * 64 + i * 16 + rg;
            int gc = col0 + wc * 64 + j * 16 + cg;
            float bb = bo[gc];
#pragma unroll
            for (int r = 0; r < 4; ++r)
                out[(gr + r) * 1024 + gc] = acc[i][j][r] + bb;
        }
}

extern "C" void kernel_launch(void* const* d_in, const int* in_sizes, int n_in,
                              void* d_out, int out_size, void* d_ws, size_t ws_size,
                              hipStream_t stream) {
    const float* x    = (const float*)d_in[0];
    const int*   mask = (const int*)d_in[1];
    const float* Wq   = (const float*)d_in[2];
    const float* Wk   = (const float*)d_in[3];
    const float* Wv   = (const float*)d_in[4];
    const float* Wo   = (const float*)d_in[5];
    const float* bo   = (const float*)d_in[6];
    float* out = (float*)d_out;

    const size_t qkv_per_b = (size_t)2048 * 3072 * 2;  // bf16 QKV per batch
    const size_t ao_per_b  = (size_t)2048 * 1024 * 2;  // bf16 attn_out per batch
    const size_t per_b = qkv_per_b + ao_per_b;         // 16 MiB
    int bchunk = (ws_size >= per_b) ? (int)(ws_size / per_b) : 1;
    if (bchunk > 4) bchunk = 4;

    unsigned short* qkv = (unsigned short*)d_ws;
    unsigned short* ao  = (unsigned short*)((char*)d_ws + (size_t)bchunk * qkv_per_b);

    for (int b0 = 0; b0 < 4; b0 += bchunk) {
        int bc = (4 - b0 < bchunk) ? (4 - b0) : bchunk;
        gemm_qkv_k<<<dim3(24, bc * 16), 256, 0, stream>>>(
            x + (size_t)b0 * 2048 * 1024, Wq, Wk, Wv, qkv);
        attn_k<<<dim3(32, 16, bc), 256, 0, stream>>>(qkv, mask, ao, b0);
        gemm_out_k<<<dim3(8, bc * 16), 256, 0, stream>>>(
            ao, Wo, bo, out + (size_t)b0 * 2048 * 1024);
    }
}

// Round 2
// 298.001 us; speedup vs baseline: 1.2202x; 1.2202x over previous
//
#include <hip/hip_runtime.h>
#include <hip/hip_bf16.h>

typedef __attribute__((ext_vector_type(8))) short sh8;
typedef __attribute__((ext_vector_type(4))) float f32x4;

#define MFMA16(a, b, c) __builtin_amdgcn_mfma_f32_16x16x32_bf16((a), (b), (c), 0, 0, 0)

// round-half-up f32->bf16 (cheap; tie-bias negligible)
__device__ __forceinline__ unsigned short f2bf(float f) {
    return (unsigned short)((__float_as_uint(f) + 0x8000u) >> 16);
}
// pack two f32 -> two bf16 in one u32 (lo in low half) via v_perm_b32
__device__ __forceinline__ unsigned int pack2bf(float lo, float hi) {
    unsigned int ul = __float_as_uint(lo) + 0x8000u;
    unsigned int uh = __float_as_uint(hi) + 0x8000u;
    return __builtin_amdgcn_perm(uh, ul, 0x07060302u);
}

// ---------------------------------------------------------------------------
// QKV projection: qkv[M x 3072] (bf16) = x[Mx1024](f32) @ W*(f32)^T
// Q part (cols < 1024) pre-scaled by 0.125 = 1/sqrt(dk).
// ---------------------------------------------------------------------------
__global__ __launch_bounds__(256) void gemm_qkv_k(
    const float* __restrict__ x, const float* __restrict__ Wq,
    const float* __restrict__ Wk, const float* __restrict__ Wv,
    unsigned short* __restrict__ qkv)
{
    __shared__ unsigned short As[128][48];
    __shared__ unsigned short Bs[128][48];
    const int tid = threadIdx.x;
    const int l = tid & 63, w = tid >> 6;
    const int wr = w >> 1, wc = w & 1;
    const long row0 = (long)blockIdx.y * 128;
    const int col0 = blockIdx.x * 128;
    const float* Wsel; int wrow0;
    if (col0 < 1024)      { Wsel = Wq; wrow0 = col0; }
    else if (col0 < 2048) { Wsel = Wk; wrow0 = col0 - 1024; }
    else                  { Wsel = Wv; wrow0 = col0 - 2048; }

    f32x4 acc[4][4] = {};
    const int fr = l & 15, fc = (l >> 4) * 8;

    for (int k0 = 0; k0 < 1024; k0 += 32) {
        __syncthreads();
#pragma unroll
        for (int p = 0; p < 4; ++p) {
            int idx = p * 256 + tid;
            int r = idx >> 3, c4 = (idx & 7) * 4;
            float4 va = *(const float4*)&x[(row0 + r) * 1024 + k0 + c4];
            uint2 ha = { pack2bf(va.x, va.y), pack2bf(va.z, va.w) };
            *(uint2*)&As[r][c4] = ha;
            float4 vb = *(const float4*)&Wsel[(long)(wrow0 + r) * 1024 + k0 + c4];
            uint2 hb = { pack2bf(vb.x, vb.y), pack2bf(vb.z, vb.w) };
            *(uint2*)&Bs[r][c4] = hb;
        }
        __syncthreads();
        sh8 af[4], bf[4];
#pragma unroll
        for (int i = 0; i < 4; ++i) {
            af[i] = *(const sh8*)&As[wr * 64 + i * 16 + fr][fc];
            bf[i] = *(const sh8*)&Bs[wc * 64 + i * 16 + fr][fc];
        }
#pragma unroll
        for (int i = 0; i < 4; ++i)
#pragma unroll
            for (int j = 0; j < 4; ++j)
                acc[i][j] = MFMA16(af[i], bf[j], acc[i][j]);
    }

    const float scale = (col0 < 1024) ? 0.125f : 1.0f;
    const int rg = (l >> 4) * 4, cg = l & 15;
#pragma unroll
    for (int i = 0; i < 4; ++i)
#pragma unroll
        for (int j = 0; j < 4; ++j) {
            long gr = row0 + wr * 64 + i * 16 + rg;
            int gc = col0 + wc * 64 + j * 16 + cg;
#pragma unroll
            for (int r = 0; r < 4; ++r)
                qkv[(gr + r) * 3072 + gc] = f2bf(acc[i][j][r] * scale);
        }
}

// ---------------------------------------------------------------------------
// Flash attention, swapped-operand form.
// Block: 128 q-rows for one (batch, head); 4 waves x 32 q-rows (2 groups of 16).
// S^T = mfma(K, Q): lane holds 16 kv scores for q = lane&15 -> in-lane softmax.
// O^T = mfma(V^T, P): acc stays q = lane&15 -> scalar rescale, packed stores.
// K/Vt tiles: 64x64 bf16, 128B rows, 16B-chunk XOR swizzle for balanced b128.
// ---------------------------------------------------------------------------
__global__ __launch_bounds__(256) void attn_k(
    const unsigned short* __restrict__ qkv, const int* __restrict__ mask,
    unsigned short* __restrict__ ao, int b0)
{
    __shared__ unsigned short Kl[64][64];
    __shared__ unsigned short Vt[64][64];
    __shared__ float biasf[64];
    __shared__ unsigned short Pl[4][16][72];

    const int tid = threadIdx.x;
    const int l = tid & 63, w = tid >> 6;
    const int fr = l & 15, hi = l >> 4;
    const int b = blockIdx.z, h = blockIdx.y, q0 = blockIdx.x * 128;
    const long base = (long)b * 2048;
    const int gmb = (b0 + b) * 2048;

    // Q fragments: 2 q-groups x 2 k-chunks, q = lane&15 (B-operand layout)
    sh8 qf[2][2];
#pragma unroll
    for (int g = 0; g < 2; ++g) {
        const unsigned short* qp = &qkv[(base + q0 + w * 32 + g * 16 + fr) * 3072 + h * 64 + hi * 8];
        qf[g][0] = *(const sh8*)qp;
        qf[g][1] = *(const sh8*)(qp + 32);
    }

    f32x4 acc[2][4] = {};                 // [group][d-tile]: O^T, lane q = fr, d = df*16+4*hi+r
    float mrow[2] = { -1e30f, -1e30f };
    float lrow[2] = { 0.f, 0.f };

    for (int kv0 = 0; kv0 < 2048; kv0 += 64) {
        __syncthreads();
        // stage K tile, chunk-swizzled: chunk' = chunk ^ (row&7)
#pragma unroll
        for (int p = 0; p < 2; ++p) {
            int idx = p * 256 + tid;
            int r = idx >> 3, cc = idx & 7;
            uint4 v = *(const uint4*)&qkv[(base + kv0 + r) * 3072 + 1024 + h * 64 + cc * 8];
            *(uint4*)&Kl[r][(cc ^ (r & 7)) * 8] = v;
        }
        // stage V transposed: Vt[d][kv], chunk' = chunk ^ ((d&7)^(d>>3))
        {
            int dc = tid & 7, kv2 = tid >> 3;
            const unsigned short* vp = &qkv[(base + kv0 + 2 * kv2) * 3072 + 2048 + h * 64 + dc * 8];
            uint4 v0 = *(const uint4*)vp;
            uint4 v1 = *(const uint4*)(vp + 3072);
            unsigned int w0[4] = { v0.x, v0.y, v0.z, v0.w };
            unsigned int w1[4] = { v1.x, v1.y, v1.z, v1.w };
            int cc = kv2 >> 2, pos = (2 * kv2) & 7;
#pragma unroll
            for (int jj = 0; jj < 4; ++jj) {
                int de = dc * 8 + 2 * jj;
                unsigned int pe = (w0[jj] & 0xffffu) | (w1[jj] << 16);
                unsigned int po = (w0[jj] >> 16) | (w1[jj] & 0xffff0000u);
                int fde = (2 * jj) ^ dc;          // (de&7)^(de>>3)
                int fdo = (2 * jj + 1) ^ dc;
                *(unsigned int*)&Vt[de][((cc ^ fde) * 8) + pos] = pe;
                *(unsigned int*)&Vt[de + 1][((cc ^ fdo) * 8) + pos] = po;
            }
        }
        if (tid < 64) biasf[tid] = (mask[gmb + kv0 + tid] == 0) ? -1e9f : 0.0f;
        __syncthreads();

        // K fragments (A-operand, m = kv_local = fr), shared by both q-groups
        sh8 kf[4][2];
#pragma unroll
        for (int t = 0; t < 4; ++t) {
            const unsigned short* kp = &Kl[t * 16 + fr][0];
#pragma unroll
            for (int c = 0; c < 2; ++c)
                kf[t][c] = *(const sh8*)&kp[((4 * c + hi) ^ (fr & 7)) * 8];
        }

#pragma unroll
        for (int g = 0; g < 2; ++g) {
            // S^T tiles: lane holds kv = 16t+4*hi+r for q-row (g*16+fr)
            f32x4 s[4] = {};
#pragma unroll
            for (int t = 0; t < 4; ++t) {
                s[t] = MFMA16(kf[t][0], qf[g][0], s[t]);
                s[t] = MFMA16(kf[t][1], qf[g][1], s[t]);
            }
            // mask bias (broadcast f32x4 reads)
#pragma unroll
            for (int t = 0; t < 4; ++t)
                s[t] += *(const f32x4*)&biasf[t * 16 + 4 * hi];

            // row max: 15 in-lane + 2 shuffles (lanes sharing fr)
            float pm = s[0][0];
#pragma unroll
            for (int t = 0; t < 4; ++t)
#pragma unroll
                for (int r = 0; r < 4; ++r) pm = fmaxf(pm, s[t][r]);
            pm = fmaxf(pm, __shfl_xor(pm, 16, 64));
            pm = fmaxf(pm, __shfl_xor(pm, 32, 64));

            float mr = mrow[g];
            if (!__all(pm <= mr)) {           // defer-max: wave-uniform skip
                float mn = fmaxf(mr, pm);
                float scl = __expf(mr - mn);
                lrow[g] *= scl;
#pragma unroll
                for (int df = 0; df < 4; ++df) acc[g][df] *= scl;
                mrow[g] = mn;
                mr = mn;
            }

            float ps = 0.f;
#pragma unroll
            for (int t = 0; t < 4; ++t)
#pragma unroll
                for (int r = 0; r < 4; ++r) {
                    float p = __expf(s[t][r] - mr);
                    s[t][r] = p;
                    ps += p;
                }
            ps += __shfl_xor(ps, 16, 64);
            ps += __shfl_xor(ps, 32, 64);
            lrow[g] += ps;

            // P -> per-wave LDS (4x b64), rows q=fr, cols kv
#pragma unroll
            for (int t = 0; t < 4; ++t) {
                uint2 pw = { pack2bf(s[t][0], s[t][1]), pack2bf(s[t][2], s[t][3]) };
                *(uint2*)&Pl[w][fr][t * 16 + hi * 4] = pw;
            }

            // O^T += V^T * P
#pragma unroll
            for (int c = 0; c < 2; ++c) {
                sh8 pa = *(const sh8*)&Pl[w][fr][c * 32 + hi * 8];
#pragma unroll
                for (int df = 0; df < 4; ++df) {
                    int d = df * 16 + fr;
                    int fd = (d & 7) ^ (d >> 3);
                    sh8 vfr = *(const sh8*)&Vt[d][((4 * c + hi) ^ fd) * 8];
                    acc[g][df] = MFMA16(vfr, pa, acc[g][df]);
                }
            }
        }
    }

    // epilogue: divide by denom, packed 8B stores
#pragma unroll
    for (int g = 0; g < 2; ++g) {
        float inv = 1.0f / lrow[g];
        long qr = base + q0 + w * 32 + g * 16 + fr;
        unsigned short* op = &ao[qr * 1024 + h * 64];
#pragma unroll
        for (int df = 0; df < 4; ++df) {
            f32x4 o = acc[g][df];
            uint2 ow = { pack2bf(o[0] * inv, o[1] * inv), pack2bf(o[2] * inv, o[3] * inv) };
            *(uint2*)&op[df * 16 + hi * 4] = ow;
        }
    }
}

// ---------------------------------------------------------------------------
// Output projection: out[Mx1024](f32) = ao[Mx1024](bf16) @ Wo(f32)^T + bo
// ---------------------------------------------------------------------------
__global__ __launch_bounds__(256) void gemm_out_k(
    const unsigned short* __restrict__ ao, const float* __restrict__ Wo,
    const float* __restrict__ bo, float* __restrict__ out)
{
    __shared__ unsigned short As[128][48];
    __shared__ unsigned short Bs[128][48];
    const int tid = threadIdx.x;
    const int l = tid & 63, w = tid >> 6;
    const int wr = w >> 1, wc = w & 1;
    const long row0 = (long)blockIdx.y * 128;
    const int col0 = blockIdx.x * 128;

    f32x4 acc[4][4] = {};
    const int fr = l & 15, fc = (l >> 4) * 8;

    for (int k0 = 0; k0 < 1024; k0 += 32) {
        __syncthreads();
#pragma unroll
        for (int p = 0; p < 2; ++p) {
            int idx = p * 256 + tid;
            int r = idx >> 2, c8 = (idx & 3) * 8;
            uint4 v = *(const uint4*)&ao[(row0 + r) * 1024 + k0 + c8];
            *(uint2*)&As[r][c8] = make_uint2(v.x, v.y);
            *(uint2*)&As[r][c8 + 4] = make_uint2(v.z, v.w);
        }
#pragma unroll
        for (int p = 0; p < 4; ++p) {
            int idx = p * 256 + tid;
            int r = idx >> 3, c4 = (idx & 7) * 4;
            float4 vb = *(const float4*)&Wo[(long)(col0 + r) * 1024 + k0 + c4];
            uint2 hb = { pack2bf(vb.x, vb.y), pack2bf(vb.z, vb.w) };
            *(uint2*)&Bs[r][c4] = hb;
        }
        __syncthreads();
        sh8 af[4], bf[4];
#pragma unroll
        for (int i = 0; i < 4; ++i) {
            af[i] = *(const sh8*)&As[wr * 64 + i * 16 + fr][fc];
            bf[i] = *(const sh8*)&Bs[wc * 64 + i * 16 + fr][fc];
        }
#pragma unroll
        for (int i = 0; i < 4; ++i)
#pragma unroll
            for (int j = 0; j < 4; ++j)
                acc[i][j] = MFMA16(af[i], bf[j], acc[i][j]);
    }

    const int rg = (l >> 4) * 4, cg = l & 15;
#pragma unroll
    for (int i = 0; i < 4; ++i)
#pragma unroll
        for (int j = 0; j < 4; ++j) {
            long gr = row0 + wr * 64 + i * 16 + rg;
            int gc = col0 + wc * 64 + j * 16 + cg;
            float bb = bo[gc];
#pragma unroll
            for (int r = 0; r < 4; ++r)
                out[(gr + r) * 1024 + gc] = acc[i][j][r] + bb;
        }
}

extern "C" void kernel_launch(void* const* d_in, const int* in_sizes, int n_in,
                              void* d_out, int out_size, void* d_ws, size_t ws_size,
                              hipStream_t stream) {
    const float* x    = (const float*)d_in[0];
    const int*   mask = (const int*)d_in[1];
    const float* Wq   = (const float*)d_in[2];
    const float* Wk   = (const float*)d_in[3];
    const float* Wv   = (const float*)d_in[4];
    const float* Wo   = (const float*)d_in[5];
    const float* bo   = (const float*)d_in[6];
    float* out = (float*)d_out;

    const size_t qkv_per_b = (size_t)2048 * 3072 * 2;  // bf16 QKV per batch
    const size_t ao_per_b  = (size_t)2048 * 1024 * 2;  // bf16 attn_out per batch
    const size_t per_b = qkv_per_b + ao_per_b;         // 16 MiB
    int bchunk = (ws_size >= per_b) ? (int)(ws_size / per_b) : 1;
    if (bchunk > 4) bchunk = 4;

    unsigned short* qkv = (unsigned short*)d_ws;
    unsigned short* ao  = (unsigned short*)((char*)d_ws + (size_t)bchunk * qkv_per_b);

    for (int b0 = 0; b0 < 4; b0 += bchunk) {
        int bc = (4 - b0 < bchunk) ? (4 - b0) : bchunk;
        gemm_qkv_k<<<dim3(24, bc * 16), 256, 0, stream>>>(
            x + (size_t)b0 * 2048 * 1024, Wq, Wk, Wv, qkv);
        attn_k<<<dim3(16, 16, bc), 256, 0, stream>>>(qkv, mask, ao, b0);
        gemm_out_k<<<dim3(8, bc * 16), 256, 0, stream>>>(
            ao, Wo, bo, out + (size_t)b0 * 2048 * 1024);
    }
}